// Round 8
// baseline (117.101 us; speedup 1.0000x reference)
//
#include <hip/hip_runtime.h>

// HeteroConv copy_u + segment_sum, CSR-rebuild formulation.
// R2: CSR kills 64M float atomics (858->436). R3: hierarchical scan (436->228).
// R4: 4-edge-parallel float4 accum (228->171). R5: rank-capturing histogram ->
// atomic-free scatter (171->130). R7: accum index prefetch, no add_bases pass
// (130->116). R8 (this): hist back to 1 edge/thread -- R7's int4 hist
// serialized 4 dependent return-atomics per thread at 29% occupancy (44us,
// latency-bound); 1/thread gives 15.6K waves and one atomic per thread.

#define SCAN_T 256
#define SCAN_SEQ 16
#define SCAN_ELEMS (SCAN_T * SCAN_SEQ)  // 4096 = 1<<12 elements per scan block

// ---- phase 1: histogram of edge_dst, capturing per-edge rank (1/thread) ----
__global__ void hist_rank_kernel(const int* __restrict__ edst,
                                 int* __restrict__ counts,
                                 int* __restrict__ rank, int n) {
    int i = blockIdx.x * blockDim.x + threadIdx.x;
    if (i < n) {
        int old = atomicAdd(&counts[edst[i]], 1);
        if (rank) rank[i] = old;
    }
}

// ---- phase 2a: per-block exclusive scan of counts (intra-block prefix) ----
__global__ void scan_blocks_kernel(const int* __restrict__ counts,
                                   int* __restrict__ offsets,
                                   int* __restrict__ block_sums, int n) {
    __shared__ int lds[SCAN_T];
    int t = threadIdx.x;
    int base = blockIdx.x * SCAN_ELEMS + t * SCAN_SEQ;

    int local[SCAN_SEQ];
    int s = 0;
    for (int k = 0; k < SCAN_SEQ; ++k) {
        int i = base + k;
        int v = (i < n) ? counts[i] : 0;
        local[k] = s;
        s += v;
    }
    lds[t] = s;
    __syncthreads();
    for (int off = 1; off < SCAN_T; off <<= 1) {
        int v = (t >= off) ? lds[t - off] : 0;
        __syncthreads();
        lds[t] += v;
        __syncthreads();
    }
    int thread_base = (t == 0) ? 0 : lds[t - 1];
    for (int k = 0; k < SCAN_SEQ; ++k) {
        int i = base + k;
        if (i < n) offsets[i] = thread_base + local[k];  // intra-block prefix
    }
    if (t == SCAN_T - 1) block_sums[blockIdx.x] = lds[t];
}

// ---- phase 2b: scan block sums in place -> exclusive bases; total ----
__global__ void scan_sums_kernel(int* __restrict__ block_sums,
                                 int* __restrict__ total_out, int nblocks) {
    __shared__ int lds[1024];
    int t = threadIdx.x;
    int v = (t < nblocks) ? block_sums[t] : 0;
    lds[t] = v;
    __syncthreads();
    for (int off = 1; off < 1024; off <<= 1) {
        int u = (t >= off) ? lds[t - off] : 0;
        __syncthreads();
        lds[t] += u;
        __syncthreads();
    }
    if (t < nblocks) block_sums[t] = lds[t] - v;  // exclusive base per block
    if (t == 1023) *total_out = lds[t];           // absolute total -> offsets[n]
}

// ---- phase 2c (tier-2 only): make offsets absolute, fill cursor ----
__global__ void add_bases_kernel(int* __restrict__ offsets,
                                 int* __restrict__ cursor,
                                 const int* __restrict__ block_bases, int n) {
    int t = threadIdx.x;
    int base = blockIdx.x * SCAN_ELEMS + t * SCAN_SEQ;
    int add = block_bases[blockIdx.x];
    for (int k = 0; k < SCAN_SEQ; ++k) {
        int i = base + k;
        if (i < n) {
            int o = offsets[i] + add;
            offsets[i] = o;
            if (cursor) cursor[i] = o;
        }
    }
}

// ---- phase 3 (tier-1): atomic-free scatter, bases applied on the fly ----
__global__ void scatter_rank_kernel(const int* __restrict__ esrc,
                                    const int* __restrict__ edst,
                                    const int* __restrict__ rank,
                                    const int* __restrict__ offsets,
                                    const int* __restrict__ bases,
                                    int* __restrict__ sorted_src, int n) {
    int i = (blockIdx.x * blockDim.x + threadIdx.x) * 4;
    if (i + 3 < n) {
        int4 s = *reinterpret_cast<const int4*>(esrc + i);
        int4 d = *reinterpret_cast<const int4*>(edst + i);
        int4 r = *reinterpret_cast<const int4*>(rank + i);
        sorted_src[offsets[d.x] + bases[d.x >> 12] + r.x] = s.x;
        sorted_src[offsets[d.y] + bases[d.y >> 12] + r.y] = s.y;
        sorted_src[offsets[d.z] + bases[d.z >> 12] + r.z] = s.z;
        sorted_src[offsets[d.w] + bases[d.w >> 12] + r.w] = s.w;
    } else {
        for (int k = 0; k < 4; ++k) {
            int ii = i + k;
            if (ii < n) {
                int d = edst[ii];
                sorted_src[offsets[d] + bases[d >> 12] + rank[ii]] = esrc[ii];
            }
        }
    }
}

// ---- phase 3 (tier-2): atomic-cursor scatter (absolute cursor) ----
__global__ void scatter_atomic_kernel(const int* __restrict__ esrc,
                                      const int* __restrict__ edst,
                                      int* __restrict__ cursor,
                                      int* __restrict__ sorted_src, int n) {
    int i = blockIdx.x * blockDim.x + threadIdx.x;
    if (i < n) {
        int pos = atomicAdd(&cursor[edst[i]], 1);
        sorted_src[pos] = esrc[i];
    }
}

// ---- phase 4: per-node accumulation with index prefetch ----
// Wave64 = 4 groups x 16 lanes; group g handles edges g, g+4, ...; lane q
// loads float4 q of the row. The NEXT edge index is prefetched one iteration
// ahead so the index load overlaps the row gather. Butterfly shfl_xor(16,32)
// folds the 4 partials; group 0 stores.
__global__ void accum_kernel(const float4* __restrict__ src4,
                             const int* __restrict__ offsets,
                             const int* __restrict__ bases,
                             const int* __restrict__ sorted_src,
                             float4* __restrict__ out4, int n_dst) {
    int node = blockIdx.x * (blockDim.x >> 6) + (threadIdx.x >> 6);
    if (node >= n_dst) return;
    int lane = threadIdx.x & 63;
    int g = lane >> 4;
    int q = lane & 15;

    int start = offsets[node] + bases[node >> 12];
    int end = (node + 1 == n_dst)
                  ? offsets[n_dst]                                  // absolute total
                  : offsets[node + 1] + bases[(node + 1) >> 12];

    float4 acc = make_float4(0.f, 0.f, 0.f, 0.f);
    int j = start + g;
    int s_next = (j < end) ? sorted_src[j] : 0;
    for (; j < end; j += 4) {
        int s = s_next;
        if (j + 4 < end) s_next = sorted_src[j + 4];  // overlap with row load
        float4 v = src4[(size_t)s * 16 + q];
        acc.x += v.x; acc.y += v.y; acc.z += v.z; acc.w += v.w;
    }
#pragma unroll
    for (int off = 16; off < 64; off <<= 1) {
        acc.x += __shfl_xor(acc.x, off);
        acc.y += __shfl_xor(acc.y, off);
        acc.z += __shfl_xor(acc.z, off);
        acc.w += __shfl_xor(acc.w, off);
    }
    if (g == 0) out4[(size_t)node * 16 + q] = acc;
}

// ---- tier-3 fallback: direct atomic version ----
__global__ void atomic_scatter_kernel(const float* __restrict__ src_emb,
                                      const int* __restrict__ esrc,
                                      const int* __restrict__ edst,
                                      float* __restrict__ out, int n_edges) {
    int tid = blockIdx.x * blockDim.x + threadIdx.x;
    int e = tid >> 4;
    int q = tid & 15;
    if (e >= n_edges) return;
    int s = esrc[e];
    int d = edst[e];
    const float4* srow = reinterpret_cast<const float4*>(src_emb);
    float4 v = srow[(size_t)s * 16 + q];
    float* orow = out + (size_t)d * 64 + (size_t)q * 4;
    atomicAdd(orow + 0, v.x);
    atomicAdd(orow + 1, v.y);
    atomicAdd(orow + 2, v.z);
    atomicAdd(orow + 3, v.w);
}

extern "C" void kernel_launch(void* const* d_in, const int* in_sizes, int n_in,
                              void* d_out, int out_size, void* d_ws, size_t ws_size,
                              hipStream_t stream) {
    const float* src_emb = (const float*)d_in[0];
    const int* edge_src  = (const int*)d_in[1];
    const int* edge_dst  = (const int*)d_in[2];
    float* out = (float*)d_out;

    const int n_edges = in_sizes[1];
    const int n_dst   = out_size / 64;  // D = 64
    const int nscan   = (n_dst + SCAN_ELEMS - 1) / SCAN_ELEMS;

    const int B = 256;
    const int egrid4 = (n_edges + 4 * B - 1) / (4 * B);   // 4 edges/thread
    const int egrid1 = (n_edges + B - 1) / B;             // 1 edge/thread
    const int nodes_per_block = B / 64;
    const int agrid = (n_dst + nodes_per_block - 1) / nodes_per_block;

    // tier-1 layout: offsets[n_dst+1] (padded to x4 ints for rank's int4
    // alignment) | rank[E] | sorted_src[E] | block_sums[nscan].
    // counts aliases sorted_src (dead after scan; requires n_dst <= n_edges).
    size_t off_pad = ((size_t)n_dst + 1 + 3) & ~(size_t)3;
    size_t need1 = (off_pad + 2 * (size_t)n_edges + nscan) * sizeof(int);
    size_t need2 = ((size_t)3 * n_dst + 1 + n_edges + nscan) * sizeof(int);

    if (ws_size >= need1 && nscan <= 1024 && n_dst <= n_edges &&
        (n_edges & 3) == 0) {
        int* offsets    = (int*)d_ws;                 // [n_dst + 1] (+pad)
        int* rank       = offsets + off_pad;          // [n_edges], 16B-aligned
        int* sorted_src = rank + n_edges;             // [n_edges]
        int* block_sums = sorted_src + n_edges;       // [nscan]
        int* counts     = sorted_src;                 // alias

        hipMemsetAsync(counts, 0, (size_t)n_dst * sizeof(int), stream);
        hist_rank_kernel<<<egrid1, B, 0, stream>>>(edge_dst, counts, rank, n_edges);
        scan_blocks_kernel<<<nscan, SCAN_T, 0, stream>>>(counts, offsets, block_sums, n_dst);
        scan_sums_kernel<<<1, 1024, 0, stream>>>(block_sums, offsets + n_dst, nscan);
        scatter_rank_kernel<<<egrid4, B, 0, stream>>>(edge_src, edge_dst, rank,
                                                      offsets, block_sums,
                                                      sorted_src, n_edges);
        accum_kernel<<<agrid, B, 0, stream>>>(
            reinterpret_cast<const float4*>(src_emb), offsets, block_sums,
            sorted_src, reinterpret_cast<float4*>(out), n_dst);
        return;
    }

    if (ws_size >= need2 && nscan <= 1024) {
        int* counts     = (int*)d_ws;                 // [n_dst]
        int* offsets    = counts + n_dst;             // [n_dst + 1]
        int* cursor     = offsets + n_dst + 1;        // [n_dst]
        int* sorted_src = cursor + n_dst;             // [n_edges]
        int* block_sums = sorted_src + n_edges;       // [nscan]

        hipMemsetAsync(counts, 0, (size_t)n_dst * sizeof(int), stream);
        hist_rank_kernel<<<egrid1, B, 0, stream>>>(edge_dst, counts, nullptr, n_edges);
        scan_blocks_kernel<<<nscan, SCAN_T, 0, stream>>>(counts, offsets, block_sums, n_dst);
        scan_sums_kernel<<<1, 1024, 0, stream>>>(block_sums, offsets + n_dst, nscan);
        add_bases_kernel<<<nscan, SCAN_T, 0, stream>>>(offsets, cursor, block_sums, n_dst);
        scatter_atomic_kernel<<<egrid1, B, 0, stream>>>(edge_src, edge_dst, cursor,
                                                        sorted_src, n_edges);
        // offsets are absolute now; pass zeroed bases
        hipMemsetAsync(block_sums, 0, (size_t)nscan * sizeof(int), stream);
        accum_kernel<<<agrid, B, 0, stream>>>(
            reinterpret_cast<const float4*>(src_emb), offsets, block_sums,
            sorted_src, reinterpret_cast<float4*>(out), n_dst);
        return;
    }

    // tier-3: direct atomic fallback
    hipMemsetAsync(d_out, 0, (size_t)out_size * sizeof(float), stream);
    int total = n_edges * 16;
    atomic_scatter_kernel<<<(total + 255) / 256, 256, 0, stream>>>(
        src_emb, edge_src, edge_dst, out, n_edges);
}